// Round 1
// baseline (429.472 us; speedup 1.0000x reference)
//
#include <hip/hip_runtime.h>
#include <math.h>

#define EPS 1e-5f
#define B_ 8
#define C_ 512
#define S_ 2048
#define IC_ 64
#define IS_ 256
#define DS_ 32

// workspace layout (float offsets)
#define OFF_CONST 0
#define OFF_THT   1024                      // thetaT [S_][512] : thetaT[t][b*64+c] = theta[b,c,t]
#define OFF_PHT   (OFF_THT + S_*C_)         // phiT   [S_][512]
#define OFF_AP    (OFF_PHT + S_*C_)         // partials [4][2][256][512]
#define OFF_A     (OFF_AP + 4*2*IS_*C_)     // A [2][256][512]  (A1, A2)
#define OFF_G     (OFF_A + 2*IS_*C_)        // g [8][256][2048]

// ---------------------------------------------------------------- k0: fold BN
__global__ __launch_bounds__(256) void k0_consts(
    const float* tg, const float* tb, const float* tm, const float* tv,
    const float* pg, const float* pb, const float* pm, const float* pv,
    const float* gg, const float* gb, const float* gm, const float* gv,
    const float* w1g, const float* w1b, const float* w1m, const float* w1v,
    const float* w2g, const float* w2b, const float* w2m, const float* w2v,
    float* cst) {
  int i = threadIdx.x;
  if (i < 64) {
    float a = tg[i] * rsqrtf(tv[i] + EPS);
    cst[i] = a; cst[64 + i] = tb[i] - tm[i] * a;
    float ap = pg[i] * rsqrtf(pv[i] + EPS);
    cst[128 + i] = ap; cst[192 + i] = pb[i] - pm[i] * ap;
  }
  if (i < 256) {
    float a = gg[i] * rsqrtf(gv[i] + EPS);
    cst[256 + i] = a; cst[512 + i] = gb[i] - gm[i] * a;
  }
  if (i < 32) {
    float a = w1g[i] * rsqrtf(w1v[i] + EPS);
    cst[768 + i] = a; cst[800 + i] = w1b[i] - w1m[i] * a;
  }
  if (i == 0) {
    float a = w2g[0] * rsqrtf(w2v[0] + EPS);
    cst[832] = a; cst[833] = w2b[0] - w2m[0] * a;
  }
}

// ------------------------------------------- k1: theta/phi = relu(bn(W @ x))
// grid (32 s-tiles, 8 b, 2 mats), block 256. Output transposed [t][b*64+m].
__global__ __launch_bounds__(256) void k1_theta_phi(
    const float* __restrict__ x, const float* __restrict__ Wt,
    const float* __restrict__ Wp, const float* __restrict__ cst,
    float* __restrict__ thetaT, float* __restrict__ phiT) {
  __shared__ float lds_x[32 * 64];   // [k][s]
  __shared__ float lds_w[64 * 32];   // [m][k]
  const int tid = threadIdx.x;
  const int s0  = blockIdx.x * 64;
  const int b   = blockIdx.y;
  const int mat = blockIdx.z;
  const float* Wm = mat ? Wp : Wt;
  const float* ac = cst + (mat ? 128 : 0);
  const float* bc = ac + 64;
  float* outT = mat ? phiT : thetaT;
  const int s  = tid & 63;
  const int mg = tid >> 6;            // wave id -> 16 m-rows each
  const float* xb = x + (size_t)b * C_ * S_;
  float acc[16];
#pragma unroll
  for (int i = 0; i < 16; ++i) acc[i] = 0.f;

  for (int kc = 0; kc < C_; kc += 32) {
    __syncthreads();
#pragma unroll
    for (int j = 0; j < 8; ++j) {
      int idx = tid + j * 256;
      lds_x[idx] = xb[(size_t)(kc + (idx >> 6)) * S_ + s0 + (idx & 63)];
      lds_w[idx] = Wm[(size_t)(idx >> 5) * C_ + kc + (idx & 31)];
    }
    __syncthreads();
#pragma unroll
    for (int k4 = 0; k4 < 8; ++k4) {
      float x0 = lds_x[(k4 * 4 + 0) * 64 + s];
      float x1 = lds_x[(k4 * 4 + 1) * 64 + s];
      float x2 = lds_x[(k4 * 4 + 2) * 64 + s];
      float x3 = lds_x[(k4 * 4 + 3) * 64 + s];
#pragma unroll
      for (int i = 0; i < 16; ++i) {
        const float4 wv = *(const float4*)&lds_w[(mg * 16 + i) * 32 + k4 * 4];
        acc[i] += x0 * wv.x + x1 * wv.y + x2 * wv.z + x3 * wv.w;
      }
    }
  }
  const int m0 = mg * 16;
  float ov[16];
#pragma unroll
  for (int i = 0; i < 16; ++i) {
    float v = ac[m0 + i] * acc[i] + bc[m0 + i];
    ov[i] = v > 0.f ? v : 0.f;
  }
  float* dst = outT + (size_t)(s0 + s) * C_ + b * IC_ + m0;
#pragma unroll
  for (int i = 0; i < 4; ++i) {
    float4 q = make_float4(ov[i*4], ov[i*4+1], ov[i*4+2], ov[i*4+3]);
    ((float4*)dst)[i] = q;
  }
}

// ------------------- k2: A1 = Wgg[:, :S] @ phiT,  A2 = Wgg[:, S:] @ thetaT
// grid (8 n-tiles, 4 o-tiles, mat*4+part), block 256. split-K over t (4x512).
__global__ __launch_bounds__(256) void k2_factor(
    const float* __restrict__ Wgg, const float* __restrict__ ws,
    float* __restrict__ Ap) {
  __shared__ float lds_b[32 * 64];   // [t][n]
  __shared__ float lds_w[64 * 32];   // [o][t]
  const int tid  = threadIdx.x;
  const int n0   = blockIdx.x * 64;
  const int o0   = blockIdx.y * 64;
  const int mat  = blockIdx.z >> 2;
  const int part = blockIdx.z & 3;
  const float* Bm = ws + (mat ? OFF_THT : OFF_PHT);
  const int t0 = part * 512;
  const int n  = tid & 63;
  const int og = tid >> 6;
  float acc[16];
#pragma unroll
  for (int i = 0; i < 16; ++i) acc[i] = 0.f;

  for (int kc = 0; kc < 512; kc += 32) {
    __syncthreads();
#pragma unroll
    for (int j = 0; j < 8; ++j) {
      int idx = tid + j * 256;
      lds_b[idx] = Bm[(size_t)(t0 + kc + (idx >> 6)) * C_ + n0 + (idx & 63)];
      lds_w[idx] = Wgg[(size_t)(o0 + (idx >> 5)) * (2 * S_) + mat * S_ + t0 + kc + (idx & 31)];
    }
    __syncthreads();
#pragma unroll
    for (int k4 = 0; k4 < 8; ++k4) {
      float x0 = lds_b[(k4 * 4 + 0) * 64 + n];
      float x1 = lds_b[(k4 * 4 + 1) * 64 + n];
      float x2 = lds_b[(k4 * 4 + 2) * 64 + n];
      float x3 = lds_b[(k4 * 4 + 3) * 64 + n];
#pragma unroll
      for (int i = 0; i < 16; ++i) {
        const float4 wv = *(const float4*)&lds_w[(og * 16 + i) * 32 + k4 * 4];
        acc[i] += x0 * wv.x + x1 * wv.y + x2 * wv.z + x3 * wv.w;
      }
    }
  }
  float* dst = Ap + (((size_t)part * 2 + mat) * IS_ + o0 + og * 16) * C_ + n0 + n;
#pragma unroll
  for (int i = 0; i < 16; ++i) dst[(size_t)i * C_] = acc[i];
}

// ------------------------------------------------- k2b: reduce 4 partials
__global__ __launch_bounds__(256) void k2b_reduce(float* __restrict__ ws) {
  const float* Ap = ws + OFF_AP;
  float* A = ws + OFF_A;
  int idx = blockIdx.x * 256 + threadIdx.x;   // 0..65535
#pragma unroll
  for (int r = 0; r < 4; ++r) {
    int i = idx + r * 65536;                  // 0..262143
    A[i] = Ap[i] + Ap[i + 262144] + Ap[i + 2 * 262144] + Ap[i + 3 * 262144];
  }
}

// ---------------- k3: g = relu(bn(A1_b @ theta_b + A2_b @ phi_b))  [b][o][s]
// grid (32 s-tiles, 2 o-halves, 8 b), block 256. Two operand phases share LDS.
__global__ __launch_bounds__(256) void k3_g(float* __restrict__ ws) {
  __shared__ float lds_a[128 * 64];   // [o_local][c]   32KB
  __shared__ float lds_t[64 * 65];    // [s][c] padded  16.25KB
  const int tid = threadIdx.x;
  const int s0  = blockIdx.x * 64;
  const int o0  = blockIdx.y * 128;
  const int b   = blockIdx.z;
  const int s   = tid & 63;
  const int og  = tid >> 6;           // 4 groups x 32 o each
  const float* A  = ws + OFF_A;
  const float* cst = ws + OFF_CONST;
  float acc[32];
#pragma unroll
  for (int i = 0; i < 32; ++i) acc[i] = 0.f;

  for (int mat = 0; mat < 2; ++mat) {
    const float* Asrc = A + (size_t)mat * IS_ * C_;
    const float* Tsrc = ws + (mat ? OFF_PHT : OFF_THT);  // A1 pairs theta, A2 pairs phi
    __syncthreads();
#pragma unroll
    for (int j = 0; j < 32; ++j) {
      int idx = tid + j * 256;     // 8192 = 128 x 64
      lds_a[idx] = Asrc[(size_t)(o0 + (idx >> 6)) * C_ + b * IC_ + (idx & 63)];
    }
#pragma unroll
    for (int j = 0; j < 16; ++j) {
      int idx = tid + j * 256;     // 4096 = 64 x 64
      lds_t[(idx >> 6) * 65 + (idx & 63)] =
          Tsrc[(size_t)(s0 + (idx >> 6)) * C_ + b * IC_ + (idx & 63)];
    }
    __syncthreads();
#pragma unroll
    for (int c4 = 0; c4 < 16; ++c4) {
      float t0v = lds_t[s * 65 + c4 * 4 + 0];
      float t1v = lds_t[s * 65 + c4 * 4 + 1];
      float t2v = lds_t[s * 65 + c4 * 4 + 2];
      float t3v = lds_t[s * 65 + c4 * 4 + 3];
#pragma unroll
      for (int i = 0; i < 32; ++i) {
        const float4 av = *(const float4*)&lds_a[(og * 32 + i) * 64 + c4 * 4];
        acc[i] += t0v * av.x + t1v * av.y + t2v * av.z + t3v * av.w;
      }
    }
  }
  float* gbuf = ws + OFF_G;
#pragma unroll
  for (int i = 0; i < 32; ++i) {
    int o = o0 + og * 32 + i;
    float v = cst[256 + o] * acc[i] + cst[512 + o];
    v = v > 0.f ? v : 0.f;
    gbuf[((size_t)b * IS_ + o) * S_ + s0 + s] = v;
  }
}

// --------- k4: y=relu(bn(W1@g)); ys=bn(W2@y); gate=sigmoid; out = x * gate
// grid (32 s-tiles, 8 b), block 256. g staged in two c-halves (<64KB LDS).
__global__ __launch_bounds__(256) void k4_final(
    const float* __restrict__ x, const float* __restrict__ W1,
    const float* __restrict__ W2, float* __restrict__ ws,
    float* __restrict__ out) {
  __shared__ float lds_g[128 * 65];   // 33.28KB
  __shared__ float lds_y[32 * 65];    // 8.32KB
  __shared__ float lds_gate[64];
  const int tid = threadIdx.x;
  const int s0  = blockIdx.x * 64;
  const int b   = blockIdx.y;
  const int s   = tid & 63;
  const int og  = tid >> 6;           // 4 groups x 8 y-rows
  const float* cst  = ws + OFF_CONST;
  const float* gsrc = ws + OFF_G + (size_t)b * IS_ * S_;
  float acc[8];
#pragma unroll
  for (int j = 0; j < 8; ++j) acc[j] = 0.f;

  for (int half = 0; half < 2; ++half) {
    __syncthreads();
#pragma unroll
    for (int j = 0; j < 32; ++j) {
      int idx = tid + j * 256;       // 8192 = 128 x 64
      lds_g[(idx >> 6) * 65 + (idx & 63)] =
          gsrc[(size_t)(half * 128 + (idx >> 6)) * S_ + s0 + (idx & 63)];
    }
    __syncthreads();
#pragma unroll
    for (int c4 = 0; c4 < 32; ++c4) {
      float g0 = lds_g[(c4 * 4 + 0) * 65 + s];
      float g1 = lds_g[(c4 * 4 + 1) * 65 + s];
      float g2 = lds_g[(c4 * 4 + 2) * 65 + s];
      float g3 = lds_g[(c4 * 4 + 3) * 65 + s];
#pragma unroll
      for (int j = 0; j < 8; ++j) {
        const float4 w = *(const float4*)&W1[(size_t)(og * 8 + j) * IS_ + half * 128 + c4 * 4];
        acc[j] += g0 * w.x + g1 * w.y + g2 * w.z + g3 * w.w;
      }
    }
  }
#pragma unroll
  for (int j = 0; j < 8; ++j) {
    int o = og * 8 + j;
    float v = cst[768 + o] * acc[j] + cst[800 + o];
    lds_y[o * 65 + s] = v > 0.f ? v : 0.f;
  }
  __syncthreads();
  if (tid < 64) {
    float sum = 0.f;
#pragma unroll
    for (int c = 0; c < 32; ++c) sum += W2[c] * lds_y[c * 65 + tid];
    float ys = cst[832] * sum + cst[833];
    lds_gate[tid] = 1.f / (1.f + expf(-ys));
  }
  __syncthreads();
  const float* xb = x + (size_t)b * C_ * S_ + s0;
  float* ob = out + (size_t)b * C_ * S_ + s0;
#pragma unroll
  for (int j = 0; j < 32; ++j) {
    int idx = tid + j * 256;          // 8192 float4 slots = 512ch x 16
    int ch = idx >> 4;
    int sc = (idx & 15) * 4;
    const float4 xv = *(const float4*)&xb[(size_t)ch * S_ + sc];
    float4 ov;
    ov.x = xv.x * lds_gate[sc + 0];
    ov.y = xv.y * lds_gate[sc + 1];
    ov.z = xv.z * lds_gate[sc + 2];
    ov.w = xv.w * lds_gate[sc + 3];
    *(float4*)&ob[(size_t)ch * S_ + sc] = ov;
  }
}

// ---------------------------------------------------------------------------
extern "C" void kernel_launch(void* const* d_in, const int* in_sizes, int n_in,
                              void* d_out, int out_size, void* d_ws, size_t ws_size,
                              hipStream_t stream) {
  const float* x   = (const float*)d_in[0];
  const float* Wt  = (const float*)d_in[1];
  const float* tg  = (const float*)d_in[2];
  const float* tb  = (const float*)d_in[3];
  const float* tm  = (const float*)d_in[4];
  const float* tv  = (const float*)d_in[5];
  const float* Wp  = (const float*)d_in[6];
  const float* pg  = (const float*)d_in[7];
  const float* pb  = (const float*)d_in[8];
  const float* pm  = (const float*)d_in[9];
  const float* pv  = (const float*)d_in[10];
  const float* Wgg = (const float*)d_in[11];
  const float* ggg = (const float*)d_in[12];
  const float* ggb = (const float*)d_in[13];
  const float* ggm = (const float*)d_in[14];
  const float* ggv = (const float*)d_in[15];
  const float* W1  = (const float*)d_in[16];
  const float* w1g = (const float*)d_in[17];
  const float* w1b = (const float*)d_in[18];
  const float* w1m = (const float*)d_in[19];
  const float* w1v = (const float*)d_in[20];
  const float* W2  = (const float*)d_in[21];
  const float* w2g = (const float*)d_in[22];
  const float* w2b = (const float*)d_in[23];
  const float* w2m = (const float*)d_in[24];
  const float* w2v = (const float*)d_in[25];
  float* ws  = (float*)d_ws;
  float* out = (float*)d_out;

  k0_consts<<<1, 256, 0, stream>>>(tg, tb, tm, tv, pg, pb, pm, pv,
                                   ggg, ggb, ggm, ggv, w1g, w1b, w1m, w1v,
                                   w2g, w2b, w2m, w2v, ws + OFF_CONST);
  k1_theta_phi<<<dim3(S_ / 64, B_, 2), 256, 0, stream>>>(
      x, Wt, Wp, ws + OFF_CONST, ws + OFF_THT, ws + OFF_PHT);
  k2_factor<<<dim3(8, 4, 8), 256, 0, stream>>>(Wgg, ws, ws + OFF_AP);
  k2b_reduce<<<256, 256, 0, stream>>>(ws);
  k3_g<<<dim3(32, 2, 8), 256, 0, stream>>>(ws);
  k4_final<<<dim3(32, 8), 256, 0, stream>>>(x, W1, W2, ws, out);
}

// Round 2
// 144.314 us; speedup vs baseline: 2.9760x; 2.9760x over previous
//
#include <hip/hip_runtime.h>
#include <math.h>

#define EPS 1e-5f
#define B_ 8
#define C_ 512
#define S_ 2048
#define IC_ 64
#define IS_ 256
#define DS_ 32

// ws layout (float offsets)
#define OFF_CONST 0
#define OFF_THT   1024                       // thetaT [S_][512]: [t][b*64+c]
#define OFF_PHT   (OFF_THT + S_*C_)          // phiT   [S_][512]
#define OFF_A     (OFF_PHT + S_*C_)          // A [2][256][512]
#define OFF_G     (OFF_A + 2*IS_*C_)         // g [8][256][2048]
#define OFF_AP    OFF_G                      // partials [8][2][256][512] (aliased; dead before k3)
#define OFF_GATE  (OFF_G + B_*IS_*S_)        // gate [8][2048]

// ---------------------------------------------------------------- k0: fold BN
__global__ __launch_bounds__(256) void k0_consts(
    const float* tg, const float* tb, const float* tm, const float* tv,
    const float* pg, const float* pb, const float* pm, const float* pv,
    const float* gg, const float* gb, const float* gm, const float* gv,
    const float* w1g, const float* w1b, const float* w1m, const float* w1v,
    const float* w2g, const float* w2b, const float* w2m, const float* w2v,
    float* cst) {
  int i = threadIdx.x;
  if (i < 64) {
    float a = tg[i] * rsqrtf(tv[i] + EPS);
    cst[i] = a; cst[64 + i] = tb[i] - tm[i] * a;
    float ap = pg[i] * rsqrtf(pv[i] + EPS);
    cst[128 + i] = ap; cst[192 + i] = pb[i] - pm[i] * ap;
  }
  if (i < 256) {
    float a = gg[i] * rsqrtf(gv[i] + EPS);
    cst[256 + i] = a; cst[512 + i] = gb[i] - gm[i] * a;
  }
  if (i < 32) {
    float a = w1g[i] * rsqrtf(w1v[i] + EPS);
    cst[768 + i] = a; cst[800 + i] = w1b[i] - w1m[i] * a;
  }
  if (i == 0) {
    float a = w2g[0] * rsqrtf(w2v[0] + EPS);
    cst[832] = a; cst[833] = w2b[0] - w2m[0] * a;
  }
}

// ------------------------------------------- k1: theta/phi = relu(bn(W @ x))
// grid (32 s-tiles, 8 b, 2 mats), block 256. 4x4 register tile per thread.
__global__ __launch_bounds__(256) void k1_theta_phi(
    const float* __restrict__ x, const float* __restrict__ Wt,
    const float* __restrict__ Wp, const float* __restrict__ cst,
    float* __restrict__ thetaT, float* __restrict__ phiT) {
  __shared__ float lds_a[64 * 68];   // [m][k] pad 68
  __shared__ float lds_b[64 * 64];   // [k][s]
  const int tid = threadIdx.x;
  const int s0  = blockIdx.x * 64;
  const int b   = blockIdx.y;
  const int mt  = blockIdx.z;
  const float* Wsrc = mt ? Wp : Wt;
  const float* xb   = x + (size_t)b * C_ * S_;
  const int tm = tid >> 4, ts = tid & 15;
  float acc[4][4] = {};

  for (int kc = 0; kc < C_; kc += 64) {
    __syncthreads();
#pragma unroll
    for (int p = 0; p < 4; ++p) {
      int f = tid + p * 256;           // 0..1023
      int row = f >> 4, c4 = f & 15;
      float4 wa = *(const float4*)&Wsrc[(size_t)row * C_ + kc + c4 * 4];
      *(float4*)&lds_a[row * 68 + c4 * 4] = wa;
      float4 xv = *(const float4*)&xb[(size_t)(kc + row) * S_ + s0 + c4 * 4];
      *(float4*)&lds_b[row * 64 + c4 * 4] = xv;
    }
    __syncthreads();
#pragma unroll 4
    for (int k4 = 0; k4 < 16; ++k4) {
      float4 bv[4], av[4];
#pragma unroll
      for (int kk = 0; kk < 4; ++kk)
        bv[kk] = *(const float4*)&lds_b[(k4 * 4 + kk) * 64 + ts * 4];
#pragma unroll
      for (int i = 0; i < 4; ++i)
        av[i] = *(const float4*)&lds_a[(tm * 4 + i) * 68 + k4 * 4];
#pragma unroll
      for (int i = 0; i < 4; ++i) {
#pragma unroll
        for (int kk = 0; kk < 4; ++kk) {
          float a = ((const float*)&av[i])[kk];
#pragma unroll
          for (int j = 0; j < 4; ++j)
            acc[i][j] += a * ((const float*)&bv[kk])[j];
        }
      }
    }
  }
  const float* ac = cst + mt * 128;
  float* outT = mt ? phiT : thetaT;
#pragma unroll
  for (int j = 0; j < 4; ++j) {
    float4 q;
#pragma unroll
    for (int i = 0; i < 4; ++i) {
      int m = tm * 4 + i;
      float v = ac[m] * acc[i][j] + ac[64 + m];
      ((float*)&q)[i] = v > 0.f ? v : 0.f;
    }
    *(float4*)&outT[(size_t)(s0 + ts * 4 + j) * C_ + b * IC_ + tm * 4] = q;
  }
}

// -------- k2: A[mat] = Wgg[:, mat*S:(mat+1)*S] @ (mat? thetaT : phiT)
// grid (8 n-tiles, 4 o-tiles, mat*8+part), block 256. split-K 8 (K=256 each).
__global__ __launch_bounds__(256) void k2_factor(
    const float* __restrict__ Wgg, const float* __restrict__ ws,
    float* __restrict__ Ap) {
  __shared__ float lds_a[64 * 68];   // [o][t] pad 68
  __shared__ float lds_b[64 * 64];   // [t][n]
  const int tid  = threadIdx.x;
  const int n0   = blockIdx.x * 64;
  const int o0   = blockIdx.y * 64;
  const int mat  = blockIdx.z >> 3;
  const int part = blockIdx.z & 7;
  const float* Bm = ws + (mat ? OFF_THT : OFF_PHT);
  const int t0 = part * 256;
  const int tm = tid >> 4, ts = tid & 15;
  float acc[4][4] = {};

  for (int kc = 0; kc < 256; kc += 64) {
    __syncthreads();
#pragma unroll
    for (int p = 0; p < 4; ++p) {
      int f = tid + p * 256;
      int row = f >> 4, c4 = f & 15;
      float4 wa = *(const float4*)&Wgg[(size_t)(o0 + row) * (2 * S_) + mat * S_ + t0 + kc + c4 * 4];
      *(float4*)&lds_a[row * 68 + c4 * 4] = wa;
      float4 bv = *(const float4*)&Bm[(size_t)(t0 + kc + row) * C_ + n0 + c4 * 4];
      *(float4*)&lds_b[row * 64 + c4 * 4] = bv;
    }
    __syncthreads();
#pragma unroll 4
    for (int k4 = 0; k4 < 16; ++k4) {
      float4 bv[4], av[4];
#pragma unroll
      for (int kk = 0; kk < 4; ++kk)
        bv[kk] = *(const float4*)&lds_b[(k4 * 4 + kk) * 64 + ts * 4];
#pragma unroll
      for (int i = 0; i < 4; ++i)
        av[i] = *(const float4*)&lds_a[(tm * 4 + i) * 68 + k4 * 4];
#pragma unroll
      for (int i = 0; i < 4; ++i) {
#pragma unroll
        for (int kk = 0; kk < 4; ++kk) {
          float a = ((const float*)&av[i])[kk];
#pragma unroll
          for (int j = 0; j < 4; ++j)
            acc[i][j] += a * ((const float*)&bv[kk])[j];
        }
      }
    }
  }
#pragma unroll
  for (int i = 0; i < 4; ++i) {
    float4 q;
#pragma unroll
    for (int j = 0; j < 4; ++j) ((float*)&q)[j] = acc[i][j];
    *(float4*)&Ap[(((size_t)part * 2 + mat) * IS_ + o0 + tm * 4 + i) * C_ + n0 + ts * 4] = q;
  }
}

// ------------------------------------------------- k2b: reduce 8 partials
__global__ __launch_bounds__(256) void k2b_reduce(float* __restrict__ ws) {
  int f = blockIdx.x * 256 + threadIdx.x;   // 0..65535 float4 slots
  const float4* ap = (const float4*)(ws + OFF_AP);
  float4* a = (float4*)(ws + OFF_A);
  float4 s = ap[f];
#pragma unroll
  for (int p = 1; p < 8; ++p) {
    float4 t = ap[f + p * 65536];
    s.x += t.x; s.y += t.y; s.z += t.z; s.w += t.w;
  }
  a[f] = s;
}

// ---------------- k3: g = relu(bn(A0 @ thetaT_b + A1 @ phiT_b))  [b][o][s]
// grid (32 s-tiles, 4 o-tiles, 8 b), block 256. Single K=128 tile, 1 barrier.
__global__ __launch_bounds__(256) void k3_g(float* __restrict__ ws) {
  __shared__ float lds_a[64 * 132];   // [o][k] pad 132
  __shared__ float lds_t[64 * 132];   // [s][k] pad 132
  const int tid = threadIdx.x;
  const int s0  = blockIdx.x * 64;
  const int o0  = blockIdx.y * 64;
  const int b   = blockIdx.z;
  const int tm = tid >> 4, ts = tid & 15;
  const float* A   = ws + OFF_A;
  const float* cst = ws + OFF_CONST;
  float acc[4][4] = {};

#pragma unroll
  for (int p = 0; p < 8; ++p) {
    int f = tid + p * 256;             // 0..2047
    int row = f >> 5, c8 = f & 31;     // row 0..63, c8 0..31
    int mat = c8 >> 4, c4 = c8 & 15;
    float4 a4 = *(const float4*)&A[((size_t)mat * IS_ + o0 + row) * C_ + b * IC_ + c4 * 4];
    *(float4*)&lds_a[row * 132 + c8 * 4] = a4;
    const float* Tsrc = ws + (mat ? OFF_PHT : OFF_THT);
    float4 t4 = *(const float4*)&Tsrc[(size_t)(s0 + row) * C_ + b * IC_ + c4 * 4];
    *(float4*)&lds_t[row * 132 + c8 * 4] = t4;
  }
  __syncthreads();
#pragma unroll 4
  for (int k4 = 0; k4 < 32; ++k4) {
    float4 av[4], bt[4];
#pragma unroll
    for (int i = 0; i < 4; ++i)
      av[i] = *(const float4*)&lds_a[(tm * 4 + i) * 132 + k4 * 4];
#pragma unroll
    for (int j = 0; j < 4; ++j)
      bt[j] = *(const float4*)&lds_t[(ts + 16 * j) * 132 + k4 * 4];
#pragma unroll
    for (int i = 0; i < 4; ++i) {
#pragma unroll
      for (int j = 0; j < 4; ++j) {
        acc[i][j] += av[i].x * bt[j].x + av[i].y * bt[j].y +
                     av[i].z * bt[j].z + av[i].w * bt[j].w;
      }
    }
  }
  float* g = ws + OFF_G;
#pragma unroll
  for (int i = 0; i < 4; ++i) {
    int o = o0 + tm * 4 + i;
    float sc = cst[256 + o], bi = cst[512 + o];
#pragma unroll
    for (int j = 0; j < 4; ++j) {
      float v = sc * acc[i][j] + bi;
      g[((size_t)b * IS_ + o) * S_ + s0 + ts + 16 * j] = v > 0.f ? v : 0.f;
    }
  }
}

// --------- k4a: y=relu(bn(W1@g)); ys=bn(W2@y); gate=sigmoid -> ws[GATE]
__global__ __launch_bounds__(256) void k4a_gate(
    const float* __restrict__ W1, const float* __restrict__ W2,
    float* __restrict__ ws) {
  __shared__ float lds_g[128 * 65];
  __shared__ float lds_y[32 * 65];
  const int tid = threadIdx.x;
  const int s0  = blockIdx.x * 64;
  const int b   = blockIdx.y;
  const int s   = tid & 63;
  const int og  = tid >> 6;
  const float* cst  = ws + OFF_CONST;
  const float* gsrc = ws + OFF_G + (size_t)b * IS_ * S_;
  float acc[8] = {};

  for (int half = 0; half < 2; ++half) {
    __syncthreads();
#pragma unroll
    for (int j = 0; j < 32; ++j) {
      int idx = tid + j * 256;       // 8192 = 128 x 64
      lds_g[(idx >> 6) * 65 + (idx & 63)] =
          gsrc[(size_t)(half * 128 + (idx >> 6)) * S_ + s0 + (idx & 63)];
    }
    __syncthreads();
#pragma unroll
    for (int c4 = 0; c4 < 32; ++c4) {
      float g0 = lds_g[(c4 * 4 + 0) * 65 + s];
      float g1 = lds_g[(c4 * 4 + 1) * 65 + s];
      float g2 = lds_g[(c4 * 4 + 2) * 65 + s];
      float g3 = lds_g[(c4 * 4 + 3) * 65 + s];
#pragma unroll
      for (int j = 0; j < 8; ++j) {
        const float4 w = *(const float4*)&W1[(size_t)(og * 8 + j) * IS_ + half * 128 + c4 * 4];
        acc[j] += g0 * w.x + g1 * w.y + g2 * w.z + g3 * w.w;
      }
    }
  }
#pragma unroll
  for (int j = 0; j < 8; ++j) {
    int o = og * 8 + j;
    float v = cst[768 + o] * acc[j] + cst[800 + o];
    lds_y[o * 65 + s] = v > 0.f ? v : 0.f;
  }
  __syncthreads();
  if (tid < 64) {
    float sum = 0.f;
#pragma unroll
    for (int c = 0; c < 32; ++c) sum += W2[c] * lds_y[c * 65 + tid];
    float ys = cst[832] * sum + cst[833];
    ws[OFF_GATE + (size_t)b * S_ + s0 + tid] = 1.f / (1.f + expf(-ys));
  }
}

// --------------------------- k4b: out = x * gate  (pure stream, float4)
__global__ __launch_bounds__(256) void k4b_mul(
    const float* __restrict__ x, const float* __restrict__ ws,
    float* __restrict__ out) {
  const float* gate = ws + OFF_GATE;
  size_t i0 = (size_t)blockIdx.x * 256 + threadIdx.x;
  for (size_t f = i0; f < 2097152; f += 524288) {  // 8*512*2048/4 float4s
    size_t elem = f * 4;
    int b = (int)(elem >> 20);          // / (512*2048)
    int s = (int)(elem & 2047);
    float4 xv = *(const float4*)&x[elem];
    float4 gv = *(const float4*)&gate[(size_t)b * S_ + s];
    float4 ov;
    ov.x = xv.x * gv.x; ov.y = xv.y * gv.y;
    ov.z = xv.z * gv.z; ov.w = xv.w * gv.w;
    *(float4*)&out[elem] = ov;
  }
}

// ---------------------------------------------------------------------------
extern "C" void kernel_launch(void* const* d_in, const int* in_sizes, int n_in,
                              void* d_out, int out_size, void* d_ws, size_t ws_size,
                              hipStream_t stream) {
  const float* x   = (const float*)d_in[0];
  const float* Wt  = (const float*)d_in[1];
  const float* tg  = (const float*)d_in[2];
  const float* tb  = (const float*)d_in[3];
  const float* tm  = (const float*)d_in[4];
  const float* tv  = (const float*)d_in[5];
  const float* Wp  = (const float*)d_in[6];
  const float* pg  = (const float*)d_in[7];
  const float* pb  = (const float*)d_in[8];
  const float* pm  = (const float*)d_in[9];
  const float* pv  = (const float*)d_in[10];
  const float* Wgg = (const float*)d_in[11];
  const float* ggg = (const float*)d_in[12];
  const float* ggb = (const float*)d_in[13];
  const float* ggm = (const float*)d_in[14];
  const float* ggv = (const float*)d_in[15];
  const float* W1  = (const float*)d_in[16];
  const float* w1g = (const float*)d_in[17];
  const float* w1b = (const float*)d_in[18];
  const float* w1m = (const float*)d_in[19];
  const float* w1v = (const float*)d_in[20];
  const float* W2  = (const float*)d_in[21];
  const float* w2g = (const float*)d_in[22];
  const float* w2b = (const float*)d_in[23];
  const float* w2m = (const float*)d_in[24];
  const float* w2v = (const float*)d_in[25];
  float* ws  = (float*)d_ws;
  float* out = (float*)d_out;

  k0_consts<<<1, 256, 0, stream>>>(tg, tb, tm, tv, pg, pb, pm, pv,
                                   ggg, ggb, ggm, ggv, w1g, w1b, w1m, w1v,
                                   w2g, w2b, w2m, w2v, ws + OFF_CONST);
  k1_theta_phi<<<dim3(S_ / 64, B_, 2), 256, 0, stream>>>(
      x, Wt, Wp, ws + OFF_CONST, ws + OFF_THT, ws + OFF_PHT);
  k2_factor<<<dim3(8, 4, 16), 256, 0, stream>>>(Wgg, ws, ws + OFF_AP);
  k2b_reduce<<<256, 256, 0, stream>>>(ws);
  k3_g<<<dim3(32, 4, 8), 256, 0, stream>>>(ws);
  k4a_gate<<<dim3(32, 8), 256, 0, stream>>>(W1, W2, ws);
  k4b_mul<<<2048, 256, 0, stream>>>(x, ws, out);
}